// Round 3
// baseline (544.756 us; speedup 1.0000x reference)
//
#include <hip/hip_runtime.h>
#include <hip/hip_bf16.h>

#define BS 256

// ---------------------------------------------------------------------------
// Kernel 1: token histogram -> masked mean embed -> fused X@w1+b1 -> M [N,16]
// ---------------------------------------------------------------------------
__global__ void encode_kernel(const int* __restrict__ seq,
                              const float* __restrict__ xcov,
                              const float* __restrict__ embed,   // 6x16 f32
                              const float* __restrict__ w1,      // 17x16 f32
                              const float* __restrict__ b1,      // 16 f32
                              float* __restrict__ M, int N) {
    __shared__ float sE[96];
    __shared__ float sW[272];
    __shared__ float sB[16];
    int tid = threadIdx.x;
    for (int i = tid; i < 96; i += BS) sE[i] = embed[i];
    for (int i = tid; i < 272; i += BS) sW[i] = w1[i];
    if (tid < 16) sB[tid] = b1[tid];
    __syncthreads();
    int n = blockIdx.x * BS + tid;
    if (n >= N) return;

    const int4* t4 = (const int4*)(seq + (size_t)n * 64);
    int c1 = 0, c2 = 0, c3 = 0, c4 = 0, c5 = 0;
#pragma unroll
    for (int i = 0; i < 16; i++) {
        int4 v = t4[i];
        c1 += (v.x == 1) + (v.y == 1) + (v.z == 1) + (v.w == 1);
        c2 += (v.x == 2) + (v.y == 2) + (v.z == 2) + (v.w == 2);
        c3 += (v.x == 3) + (v.y == 3) + (v.z == 3) + (v.w == 3);
        c4 += (v.x == 4) + (v.y == 4) + (v.z == 4) + (v.w == 4);
        c5 += (v.x == 5) + (v.y == 5) + (v.z == 5) + (v.w == 5);
    }
    float f1 = (float)c1, f2 = (float)c2, f3 = (float)c3, f4 = (float)c4, f5 = (float)c5;
    float tot = f1 + f2 + f3 + f4 + f5;
    float inv = 1.0f / fmaxf(tot, 1.0f);

    float h[16];
#pragma unroll
    for (int j = 0; j < 16; j++)
        h[j] = (f1 * sE[16 + j] + f2 * sE[32 + j] + f3 * sE[48 + j] +
                f4 * sE[64 + j] + f5 * sE[80 + j]) * inv;

    float xc = xcov[n];
    float o[16];
#pragma unroll
    for (int j = 0; j < 16; j++) o[j] = sB[j] + xc * sW[256 + j];
#pragma unroll
    for (int k = 0; k < 16; k++) {
        float hk = h[k];
#pragma unroll
        for (int j = 0; j < 16; j++) o[j] += hk * sW[k * 16 + j];
    }
    float4* mr = (float4*)(M + (size_t)n * 16);
    mr[0] = make_float4(o[0], o[1], o[2], o[3]);
    mr[1] = make_float4(o[4], o[5], o[6], o[7]);
    mr[2] = make_float4(o[8], o[9], o[10], o[11]);
    mr[3] = make_float4(o[12], o[13], o[14], o[15]);
}

// ---------------------------------------------------------------------------
// Kernel 2: degree via atomics (deg buffer pre-zeroed by memset)
// ---------------------------------------------------------------------------
__global__ void degree_kernel(const int* __restrict__ ei,
                              const int* __restrict__ batch,
                              float* __restrict__ deg, int E) {
    int e = blockIdx.x * BS + threadIdx.x;
    if (e >= E) return;
    int s = ei[e];
    int d = ei[E + e];
    if (batch[s] == batch[d]) atomicAdd(&deg[s], 1.0f);
}

// ---------------------------------------------------------------------------
// Kernel 3: dinv = (deg + 1 + 1e-8)^-1/2, in place
// ---------------------------------------------------------------------------
__global__ void dinv_kernel(float* __restrict__ dd, int N) {
    int n = blockIdx.x * BS + threadIdx.x;
    if (n >= N) return;
    float dg = dd[n] + 1.0f + 1e-8f;
    dd[n] = 1.0f / sqrtf(dg);
}

// ---------------------------------------------------------------------------
// Kernel 4: message scatter: agg[src] += dinv[dst] * M[dst] for valid edges
// ---------------------------------------------------------------------------
__global__ void agg_kernel(const int* __restrict__ ei,
                           const int* __restrict__ batch,
                           const float* __restrict__ dinv,
                           const float* __restrict__ M,
                           float* __restrict__ agg, int E) {
    int e = blockIdx.x * BS + threadIdx.x;
    if (e >= E) return;
    int s = ei[e];
    int d = ei[E + e];
    if (batch[s] != batch[d]) return;
    float c = dinv[d];
    const float4* m4 = (const float4*)(M + (size_t)d * 16);
    float4 v0 = m4[0], v1 = m4[1], v2 = m4[2], v3 = m4[3];
    float* a = agg + (size_t)s * 16;
    atomicAdd(a + 0,  c * v0.x); atomicAdd(a + 1,  c * v0.y);
    atomicAdd(a + 2,  c * v0.z); atomicAdd(a + 3,  c * v0.w);
    atomicAdd(a + 4,  c * v1.x); atomicAdd(a + 5,  c * v1.y);
    atomicAdd(a + 6,  c * v1.z); atomicAdd(a + 7,  c * v1.w);
    atomicAdd(a + 8,  c * v2.x); atomicAdd(a + 9,  c * v2.y);
    atomicAdd(a + 10, c * v2.z); atomicAdd(a + 11, c * v2.w);
    atomicAdd(a + 12, c * v3.x); atomicAdd(a + 13, c * v3.y);
    atomicAdd(a + 14, c * v3.z); atomicAdd(a + 15, c * v3.w);
}

// ---------------------------------------------------------------------------
// Kernel 5: H1 = relu(dinv*(agg + dinv*M)); M <- H1@w2+b2 (in place); agg <- 0
// ---------------------------------------------------------------------------
__global__ void finalize1_kernel(const float* __restrict__ dinv,
                                 float* __restrict__ M,
                                 float* __restrict__ agg,
                                 const float* __restrict__ w2,
                                 const float* __restrict__ b2, int N) {
    __shared__ float sW[256];
    __shared__ float sB[16];
    int tid = threadIdx.x;
    for (int i = tid; i < 256; i += BS) sW[i] = w2[i];
    if (tid < 16) sB[tid] = b2[tid];
    __syncthreads();
    int n = blockIdx.x * BS + tid;
    if (n >= N) return;
    float di = dinv[n];
    float4* mr = (float4*)(M + (size_t)n * 16);
    float4* ar = (float4*)(agg + (size_t)n * 16);
    float m[16], a[16];
    float4 t;
    t = mr[0]; m[0]=t.x; m[1]=t.y; m[2]=t.z; m[3]=t.w;
    t = mr[1]; m[4]=t.x; m[5]=t.y; m[6]=t.z; m[7]=t.w;
    t = mr[2]; m[8]=t.x; m[9]=t.y; m[10]=t.z; m[11]=t.w;
    t = mr[3]; m[12]=t.x; m[13]=t.y; m[14]=t.z; m[15]=t.w;
    t = ar[0]; a[0]=t.x; a[1]=t.y; a[2]=t.z; a[3]=t.w;
    t = ar[1]; a[4]=t.x; a[5]=t.y; a[6]=t.z; a[7]=t.w;
    t = ar[2]; a[8]=t.x; a[9]=t.y; a[10]=t.z; a[11]=t.w;
    t = ar[3]; a[12]=t.x; a[13]=t.y; a[14]=t.z; a[15]=t.w;
    // re-zero agg for layer 2
    float4 z = make_float4(0.f, 0.f, 0.f, 0.f);
    ar[0] = z; ar[1] = z; ar[2] = z; ar[3] = z;

    float h[16];
#pragma unroll
    for (int j = 0; j < 16; j++) h[j] = fmaxf(di * (a[j] + di * m[j]), 0.0f);

    float o[16];
#pragma unroll
    for (int j = 0; j < 16; j++) o[j] = sB[j];
#pragma unroll
    for (int k = 0; k < 16; k++) {
        float hk = h[k];
#pragma unroll
        for (int j = 0; j < 16; j++) o[j] += hk * sW[k * 16 + j];
    }
    mr[0] = make_float4(o[0], o[1], o[2], o[3]);
    mr[1] = make_float4(o[4], o[5], o[6], o[7]);
    mr[2] = make_float4(o[8], o[9], o[10], o[11]);
    mr[3] = make_float4(o[12], o[13], o[14], o[15]);
}

// ---------------------------------------------------------------------------
// Kernel 6: H2 = relu(dinv*(agg + dinv*M))
// ---------------------------------------------------------------------------
__global__ void finalize2_kernel(const float* __restrict__ dinv,
                                 const float* __restrict__ M,
                                 const float* __restrict__ agg,
                                 float* __restrict__ H2, int N) {
    int n = blockIdx.x * BS + threadIdx.x;
    if (n >= N) return;
    float di = dinv[n];
    const float4* mr = (const float4*)(M + (size_t)n * 16);
    const float4* ar = (const float4*)(agg + (size_t)n * 16);
    float4* hr = (float4*)(H2 + (size_t)n * 16);
#pragma unroll
    for (int q = 0; q < 4; q++) {
        float4 m = mr[q], a = ar[q], o;
        o.x = fmaxf(di * (a.x + di * m.x), 0.0f);
        o.y = fmaxf(di * (a.y + di * m.y), 0.0f);
        o.z = fmaxf(di * (a.z + di * m.z), 0.0f);
        o.w = fmaxf(di * (a.w + di * m.w), 0.0f);
        hr[q] = o;
    }
}

// ---------------------------------------------------------------------------
// Kernel 7: edge MLP: logits = relu([H2[s],H2[d],ea] @ we1 + be1) @ we2 + be2
// Output stored as fp32 (reference output dtype).
// ---------------------------------------------------------------------------
__global__ void edge_mlp_kernel(const int* __restrict__ ei,
                                const float* __restrict__ H2,
                                const float* __restrict__ eattr,   // E x 5 f32
                                const float* __restrict__ we1,     // 37x16 f32
                                const float* __restrict__ be1,     // 16
                                const float* __restrict__ we2,     // 16
                                const float* __restrict__ be2,     // 1
                                float* __restrict__ out, int E) {
    __shared__ float sW[592];
    __shared__ float sB[16];
    __shared__ float sV[16];
    __shared__ float sb2;
    int tid = threadIdx.x;
    for (int i = tid; i < 592; i += BS) sW[i] = we1[i];
    if (tid < 16) sB[tid] = be1[tid];
    if (tid < 16) sV[tid] = we2[tid];
    if (tid == 0) sb2 = be2[0];
    __syncthreads();
    int e = blockIdx.x * BS + tid;
    if (e >= E) return;
    int s = ei[e];
    int d = ei[E + e];
    const float4* hs4 = (const float4*)(H2 + (size_t)s * 16);
    const float4* hd4 = (const float4*)(H2 + (size_t)d * 16);
    float hs[16], hd[16];
    float4 t;
    t = hs4[0]; hs[0]=t.x; hs[1]=t.y; hs[2]=t.z; hs[3]=t.w;
    t = hs4[1]; hs[4]=t.x; hs[5]=t.y; hs[6]=t.z; hs[7]=t.w;
    t = hs4[2]; hs[8]=t.x; hs[9]=t.y; hs[10]=t.z; hs[11]=t.w;
    t = hs4[3]; hs[12]=t.x; hs[13]=t.y; hs[14]=t.z; hs[15]=t.w;
    t = hd4[0]; hd[0]=t.x; hd[1]=t.y; hd[2]=t.z; hd[3]=t.w;
    t = hd4[1]; hd[4]=t.x; hd[5]=t.y; hd[6]=t.z; hd[7]=t.w;
    t = hd4[2]; hd[8]=t.x; hd[9]=t.y; hd[10]=t.z; hd[11]=t.w;
    t = hd4[3]; hd[12]=t.x; hd[13]=t.y; hd[14]=t.z; hd[15]=t.w;
    const float* ea = eattr + (size_t)e * 5;
    float a0 = ea[0], a1 = ea[1], a2 = ea[2], a3 = ea[3], a4 = ea[4];

    float acc[16];
#pragma unroll
    for (int j = 0; j < 16; j++) acc[j] = sB[j];
#pragma unroll
    for (int k = 0; k < 16; k++) {
        float v = hs[k];
#pragma unroll
        for (int j = 0; j < 16; j++) acc[j] += v * sW[k * 16 + j];
    }
#pragma unroll
    for (int k = 0; k < 16; k++) {
        float v = hd[k];
#pragma unroll
        for (int j = 0; j < 16; j++) acc[j] += v * sW[(16 + k) * 16 + j];
    }
#pragma unroll
    for (int j = 0; j < 16; j++) {
        acc[j] += a0 * sW[512 + j] + a1 * sW[528 + j] + a2 * sW[544 + j] +
                  a3 * sW[560 + j] + a4 * sW[576 + j];
    }
    float lg = sb2;
#pragma unroll
    for (int j = 0; j < 16; j++) lg += fmaxf(acc[j], 0.0f) * sV[j];
    out[e] = lg;
}

// ---------------------------------------------------------------------------
extern "C" void kernel_launch(void* const* d_in, const int* in_sizes, int n_in,
                              void* d_out, int out_size, void* d_ws, size_t ws_size,
                              hipStream_t stream) {
    const int* seq     = (const int*)d_in[0];
    const float* xcov  = (const float*)d_in[1];
    const int* ei      = (const int*)d_in[2];
    const float* eattr = (const float*)d_in[3];
    const int* batch   = (const int*)d_in[4];
    const float* embed = (const float*)d_in[5];
    const float* w1    = (const float*)d_in[6];
    const float* b1    = (const float*)d_in[7];
    const float* w2    = (const float*)d_in[8];
    const float* b2    = (const float*)d_in[9];
    const float* we1   = (const float*)d_in[10];
    const float* be1   = (const float*)d_in[11];
    const float* we2   = (const float*)d_in[12];
    const float* be2   = (const float*)d_in[13];
    float* out         = (float*)d_out;   // fp32 output

    int N = in_sizes[1];
    int E = in_sizes[2] / 2;

    char* ws = (char*)d_ws;
    size_t off = 0;
    auto alloc = [&](size_t bytes) -> void* {
        void* p = ws + off;
        off += (bytes + 255) & ~(size_t)255;
        return p;
    };
    float* dinv = (float*)alloc((size_t)N * sizeof(float));         // deg then dinv
    float* M    = (float*)alloc((size_t)N * 16 * sizeof(float));
    float* agg  = (float*)alloc((size_t)N * 16 * sizeof(float));
    float* H2   = (float*)alloc((size_t)N * 16 * sizeof(float));

    hipMemsetAsync(dinv, 0, (size_t)N * sizeof(float), stream);
    hipMemsetAsync(agg, 0, (size_t)N * 16 * sizeof(float), stream);

    int gn = (N + BS - 1) / BS;
    int ge = (E + BS - 1) / BS;

    encode_kernel<<<gn, BS, 0, stream>>>(seq, xcov, embed, w1, b1, M, N);
    degree_kernel<<<ge, BS, 0, stream>>>(ei, batch, dinv, E);
    dinv_kernel<<<gn, BS, 0, stream>>>(dinv, N);
    agg_kernel<<<ge, BS, 0, stream>>>(ei, batch, dinv, M, agg, E);
    finalize1_kernel<<<gn, BS, 0, stream>>>(dinv, M, agg, w2, b2, N);
    agg_kernel<<<ge, BS, 0, stream>>>(ei, batch, dinv, M, agg, E);
    finalize2_kernel<<<gn, BS, 0, stream>>>(dinv, M, agg, H2, N);
    edge_mlp_kernel<<<ge, BS, 0, stream>>>(ei, H2, eattr, we1, be1, we2, be2, out, E);
}